// Round 8
// baseline (285.930 us; speedup 1.0000x reference)
//
#include <hip/hip_runtime.h>

#define D_  256
#define K_  1024
#define HW_ 1024      // 32*32
#define N_  32768     // 32*HW_

// workspace layout (bytes)
#define WS_BEST    0          // u64[32768]  (init by vq_prep)
#define WS_COUNTS  262144     // f32[1024]
#define WS_EMBSUM  266240     // f32[262144]
#define WS_LOSS    1314816    // f32
#define WS_NSUM    1314820    // f32
#define WS_ENMAX   1314824    // u32 (max ||e||^2 bits)
#define WS_ZERO0   262144     // zero range start
#define WS_ZEROLEN 1052684    // covers counts..enmax
#define WS_NEWCS   1314828    // f32[1024]
#define WS_ENORM   1318924    // f32[1024]
#define WS_ZNORM   1323020    // f32[32768]
#define WS_E16     1454096    // fp16(512*E)[1024*256] = 512 KiB (16B aligned)
#define WS_TOTAL   1978384

// output offsets (f32 elements): (z_q_st, loss, indices, new_emb, new_cs, new_es)
// NOTE: O_ZQ region doubles as zT (f32 transpose of z, [n][d]) between vq_prep
// and vq_scatter; scatter fully overwrites it afterwards.
#define O_ZQ   0
#define O_LOSS 8388608
#define O_IDX  8388609
#define O_EMB  8421377
#define O_NCS  8683521
#define O_NES  8684545

typedef unsigned short u16;
typedef _Float16 f16x8 __attribute__((ext_vector_type(8)));  // 8 f16 = 4 VGPRs
typedef float f32x4 __attribute__((ext_vector_type(4)));

// pack two f32 -> two f16 (HW v_cvt_f16_f32, rne)
__device__ __forceinline__ unsigned f16x2pack(float a, float b) {
  union { _Float16 h; unsigned short u; } ca, cb;
  ca.h = (_Float16)a; cb.h = (_Float16)b;
  return (unsigned)ca.u | ((unsigned)cb.u << 16);
}

// numpy pairwise_sum of 256 squares: two 128-halves, 8 accumulators,
// combine ((r0+r1)+(r2+r3))+((r4+r5)+(r6+r7)). __f*_rn blocks FMA contraction.
__device__ __forceinline__ float pw256_sq(const float* __restrict__ p, int stride) {
  float tot0 = 0.f, tot1 = 0.f;
#pragma unroll
  for (int h = 0; h < 2; ++h) {
    const float* q = p + h * 128 * stride;
    float r[8];
#pragma unroll
    for (int j = 0; j < 8; ++j) { float x = q[j * stride]; r[j] = __fmul_rn(x, x); }
    for (int i = 8; i < 128; i += 8)
#pragma unroll
      for (int j = 0; j < 8; ++j) {
        float x = q[(i + j) * stride];
        r[j] = __fadd_rn(r[j], __fmul_rn(x, x));
      }
    float s = __fadd_rn(__fadd_rn(__fadd_rn(r[0], r[1]), __fadd_rn(r[2], r[3])),
                        __fadd_rn(__fadd_rn(r[4], r[5]), __fadd_rn(r[6], r[7])));
    if (h == 0) tot0 = s; else tot1 = s;
  }
  return __fadd_rn(tot0, tot1);
}

// ---------------- FUSED prep: znorm + zT + best-init (z read ONCE) + E path ----------------
// Round-8 fusion: rounds 5-7 streamed z twice (norms read 128MB, zt read+write
// 256MB). Here each z-block stages its 32-token tile in LDS once: znorm is
// computed from LDS (bit-identical values, same np order) and zT written from
// LDS (coalesced 1KB rows). Blocks 1024..1027 handle enorm/enmax/E16.
__global__ void vq_prep(const float* __restrict__ z, const float* __restrict__ E,
                        float* __restrict__ znorm, float* __restrict__ enorm,
                        u16* __restrict__ E16, unsigned* __restrict__ enmax,
                        unsigned long long* __restrict__ best,
                        float* __restrict__ zT) {
  const int tid = threadIdx.x;
  const int blk = blockIdx.x;
  if (blk < 1024) {                        // z tile: 32 tokens
    __shared__ float zs[32][257];          // pad 257: (tok+d)%32 banking, conflict-free
    const int bimg = blk >> 5;
    const int hw0 = (blk & 31) << 5;
    const float* zb = z + bimg * (D_ * HW_) + hw0;
    const int n0 = bimg * HW_ + hw0;
#pragma unroll
    for (int it = 0; it < 32; ++it) {      // 8192 elems, coalesced global reads
      int idx = it * 256 + tid;
      int tok = idx & 31, d = idx >> 5;
      zs[tok][d] = zb[d * HW_ + tok];
    }
    __syncthreads();
    if (tid < 32) {
      znorm[n0 + tid] = pw256_sq(&zs[tid][0], 1);   // same values, same np order
      best[n0 + tid] = ~0ull;
    }
    // zT rows: 32 rows x 64 float4; wave = one row -> 1KB contiguous stores
    float* o = zT + (unsigned)n0 * D_;
#pragma unroll
    for (int it = 0; it < 8; ++it) {
      int oi = it * 256 + tid;
      int tok = oi >> 6, f4i = oi & 63;
      float4 v = *(const float4*)(&zs[tok][f4i * 4]);
      *(float4*)(o + tok * D_ + f4i * 4) = v;
    }
  } else {                                 // E: norms + fp16*512 conversion
    int k = (blk - 1024) * 256 + tid;      // 0..1023
    float v = pw256_sq(E + k * D_, 1);
    enorm[k] = v;
    atomicMax(enmax, __float_as_uint(v));  // v > 0 -> bit-monotone
    unsigned* E16w = (unsigned*)E16;
    for (int wd = k; wd < (K_ * D_ / 2); wd += 1024) {
      float2 x = *(const float2*)(E + 2 * wd);
      E16w[wd] = f16x2pack(512.0f * x.x, 512.0f * x.y);
    }
  }
}

// Exact reference-numerics distance for one (token, code): sequential fp32 FMA
// chain over d=0..255 (byte-identical order to the v9/reference path), then
// fl(fl(zn - 2a) + en). float4 streams from zT row + E row.
// Key=(score_bits<<32)|code -> device atomicMin; lowest code wins ties.
// noinline safe: called only AFTER the MFMA loop (no RA poison).
__device__ __attribute__((noinline)) void exact_update(
    const float* __restrict__ zTb, const float* __restrict__ E,
    int t, int c, const float* __restrict__ zn_s, const float* __restrict__ en_s,
    unsigned long long* __restrict__ best) {
  const float* zp = zTb + t * D_;
  const float* ep = E + c * D_;
  float a = 0.f;
  for (int d0 = 0; d0 < 256; d0 += 8) {
    float4 z0 = *(const float4*)(zp + d0);
    float4 z1 = *(const float4*)(zp + d0 + 4);
    float4 e0 = *(const float4*)(ep + d0);
    float4 e1 = *(const float4*)(ep + d0 + 4);
    a = __fmaf_rn(z0.x, e0.x, a); a = __fmaf_rn(z0.y, e0.y, a);
    a = __fmaf_rn(z0.z, e0.z, a); a = __fmaf_rn(z0.w, e0.w, a);
    a = __fmaf_rn(z1.x, e1.x, a); a = __fmaf_rn(z1.y, e1.y, a);
    a = __fmaf_rn(z1.z, e1.z, a); a = __fmaf_rn(z1.w, e1.w, a);
  }
  float s = __fadd_rn(__fsub_rn(zn_s[t], __fmul_rn(2.0f, a)), en_s[c & 1023]);
  unsigned long long key = ((unsigned long long)__float_as_uint(s) << 32) | (unsigned)c;
  atomicMin(&best[t], key);
}

// VALU-speed 16-lane min via DPP (quad_perm ^1, ^2, row_half_mirror, row_mirror)
template <int CTRL>
__device__ __forceinline__ float dppmin(float v) {
  int p = __builtin_amdgcn_update_dpp(0, __float_as_int(v), CTRL, 0xF, 0xF, true);
  return fminf(v, __int_as_float(p));
}

#define TCAP 160   // per-wave trigger list (expected ~24 used w/ fp16 margin)

// ---------------- MFMA distance + argmin with exact verification ----------------
// ROUND-8 GEOMETRY: 1024 blocks x 256 thr; block = 32 tokens x ALL 1024 codes.
// LDS ~23 KB -> 5-6 blocks/CU (rounds 5-7 were stuck at 2.75 blocks/CU with
// 38-40 KB blocks; two prefetch experiments were null -> the limiter is
// occupancy/latency-hiding, not in-wave pipelining). Wave owns 256 codes in
// 8 chunks of 32: acc[2][2]=16 regs; 64 steps x 4 MFMA = 256 MFMA/wave (same
// total as before). 2-bank ef ping-pong (round-6's best-measured variant).
// fp16 MFMA (z as f16, E as f16*512) -> ph = en - 2*(A/512); margin
// M = 2^-8*sqrt(zn*en_max) + 5e-4 (2x the rigorous two-sided fp16 bound).
// Approx pass only GATES; exact fp32 chain (np order) decides.
__global__ __launch_bounds__(256, 6) void vq_dist_mfma8(
    const float* __restrict__ z, const float* __restrict__ E,
    const u16* __restrict__ E16, const float* __restrict__ zT,
    const float* __restrict__ znorm, const float* __restrict__ enorm,
    const unsigned* __restrict__ enmax,
    unsigned long long* __restrict__ best_g) {
  __shared__ __align__(16) u16 zt[32 * 32 * 8];          // 16 KiB, [kb][tok(32)][8d]
  __shared__ float en_s[K_];                              // 4 KiB (all codes)
  __shared__ float zn_s[32];
  __shared__ float mg_s[32];
  __shared__ unsigned rmin_s[32];                         // bits of (min ph)+4.0
  __shared__ unsigned tcount[4];
  __shared__ unsigned tlist[4][TCAP];                     // 2.5 KiB

  const int tid = threadIdx.x;
  const int tile = blockIdx.x;               // 0..1023
  const int bimg = tile >> 5;
  const int hw0 = (tile & 31) << 5;          // 32 tokens
  const float* zb = z + bimg * (D_ * HW_) + hw0;
  const float* zTb = zT + (unsigned)(bimg * HW_ + hw0) * D_;
  unsigned long long* best = best_g + bimg * HW_ + hw0;

  if (tid < 32) {
    float zn = znorm[bimg * HW_ + hw0 + tid];
    zn_s[tid] = zn;
    float em = __uint_as_float(*enmax);
    mg_s[tid] = 0.00390625f * sqrtf(zn * em) + 5e-4f;  // fp16 margin (proven safe)
    rmin_s[tid] = 0xFFFFFFFFu;   // own-wave chunk-min always lands before read
  }
  if (tid < 4) tcount[tid] = 0;
  for (int i = tid; i < K_; i += 256) en_s[i] = enorm[i];

  // stage z tile -> f16 LDS. thread: tok = tid&31, kb = (tid>>5)*4 + r.
  {
    const int tok = tid & 31;
    const int kbase = (tid >> 5) * 4;        // 8 groups x 4 kb = 32 kb
    for (int r = 0; r < 4; ++r) {
      int kb = kbase + r;
      unsigned pk[4];
#pragma unroll
      for (int j = 0; j < 4; ++j) {
        float x0 = zb[(kb * 8 + 2 * j) * HW_ + tok];
        float x1 = zb[(kb * 8 + 2 * j + 1) * HW_ + tok];
        pk[j] = f16x2pack(x0, x1);
      }
      uint4 wv; wv.x = pk[0]; wv.y = pk[1]; wv.z = pk[2]; wv.w = pk[3];
      *(uint4*)(zt + kb * 256 + tok * 8) = wv;       // 16B, conflict-free
    }
  }
  __syncthreads();

  const int lane = tid & 63;
  const int w = tid >> 6;
  const int l15 = lane & 15, g = lane >> 4;
  const int cw = w * 256;                    // wave's code base
  const u16* Eb = E16 + (unsigned)(cw + l15) * D_ + g * 8;

  f16x8 efA[2], efB[2];
#pragma unroll
  for (int n = 0; n < 2; ++n)
    efA[n] = *(const f16x8*)(Eb + n * 16 * D_);          // prime: s=0 (ch0,kk0)

  f32x4 acc[2][2];

// one MFMA step: S = step id, EFU = bank consumed, EFF = bank filled for SN.
// No branches, no calls in the loop (rounds 2/3 lessons).
#define MSTEP(S, EFU, EFF, SN)                                                   \
  {                                                                              \
    const int kk_ = (S) & 7;                                                     \
    {                                                                            \
      const int cn_ = (SN) >> 3, kn_ = (SN) & 7;                                 \
      _Pragma("unroll")                                                          \
      for (int n = 0; n < 2; ++n)                                                \
        EFF[n] = *(const f16x8*)(Eb + (cn_ * 32 + n * 16) * D_ + kn_ * 32);      \
    }                                                                            \
    f16x8 zf_[2];                                                                \
    _Pragma("unroll")                                                            \
    for (int m = 0; m < 2; ++m)                                                  \
      zf_[m] = *(const f16x8*)(zt + (kk_ * 4 + g) * 256 + (m * 16 + l15) * 8);   \
    _Pragma("unroll")                                                            \
    for (int m = 0; m < 2; ++m)                                                  \
      _Pragma("unroll")                                                          \
      for (int n = 0; n < 2; ++n)                                                \
        acc[m][n] = __builtin_amdgcn_mfma_f32_16x16x32_f16(zf_[m], EFU[n],       \
                                                           acc[m][n], 0, 0, 0);  \
  }

  for (int s2 = 0; s2 < 64; s2 += 2) {      // 8 chunks x 8 kk
    if ((s2 & 7) == 0) {                    // chunk start: zero accumulators
      f32x4 z4 = {0.f, 0.f, 0.f, 0.f};
#pragma unroll
      for (int m = 0; m < 2; ++m)
#pragma unroll
        for (int n = 0; n < 2; ++n) acc[m][n] = z4;
    }
    MSTEP(s2, efA, efB, s2 + 1)                       // even step: use A, fill B
    MSTEP(s2 + 1, efB, efA, (s2 + 2) & 63)            // odd: use B, fill A (tail
                                                      //  wrap value never used)
    if ((s2 & 7) == 6) {                    // chunk end (after kk=7)
      const int ch = s2 >> 3;
      const int cb = cw + ch * 32;          // chunk's code base
      // ph = en - 2*(A/512) = fma(-1/256, A, en).
      // D layout: col=lane&15 (code), row=g*4+r (token).
      float enc[2];
#pragma unroll
      for (int n = 0; n < 2; ++n) enc[n] = en_s[cb + n * 16 + l15];
#pragma unroll
      for (int m = 0; m < 2; ++m)
#pragma unroll
        for (int n = 0; n < 2; ++n)
#pragma unroll
          for (int r = 0; r < 4; ++r)
            acc[m][n][r] = __builtin_fmaf(-0.00390625f, acc[m][n][r], enc[n]);
      // per-token chunk-min: 1 fmin + 4 DPP-min (pure VALU), one LDS atomic
#pragma unroll
      for (int m = 0; m < 2; ++m)
#pragma unroll
        for (int r = 0; r < 4; ++r) {
          float v = fminf(acc[m][0][r], acc[m][1][r]);
          v = dppmin<0xB1>(v);     // ^1
          v = dppmin<0x4E>(v);     // ^2
          v = dppmin<0x141>(v);    // row_half_mirror
          v = dppmin<0x140>(v);    // row_mirror
          if (l15 == 0) atomicMin(&rmin_s[m * 16 + g * 4 + r], __float_as_uint(v + 4.0f));
        }
      // triggers: ph <= runmin + M (stale/larger runmin safe: more triggers).
      // Overflow entries DROPPED but counted -> post-loop full re-verify.
#pragma unroll
      for (int m = 0; m < 2; ++m)
#pragma unroll
        for (int r = 0; r < 4; ++r) {
          int t = m * 16 + g * 4 + r;
          float thr = (__uint_as_float(rmin_s[t]) - 4.0f) + mg_s[t];
#pragma unroll
          for (int n = 0; n < 2; ++n) {
            if (acc[m][n][r] <= thr) {
              unsigned pos = atomicAdd(&tcount[w], 1u);
              if (pos < TCAP)
                tlist[w][pos] = ((unsigned)t << 16) | (unsigned)(cb + n * 16 + l15);
            }
          }
        }
    }
  }
#undef MSTEP

  // drain own wave's trigger list: exact recompute into global best
  {
    unsigned cnt = tcount[w];
    if (cnt <= TCAP) {
      for (unsigned basei = 0; basei < cnt; basei += 64) {
        unsigned i = basei + (unsigned)lane;
        if (i < cnt) {
          unsigned e = tlist[w][i];
          exact_update(zTb, E, (int)(e >> 16), (int)(e & 1023u), zn_s, en_s, best);
        }
      }
    } else {
      // overflow (astronomically rare): exactly verify this wave's whole tile
      for (unsigned i = (unsigned)lane; i < 32u * 256u; i += 64) {
        exact_update(zTb, E, (int)(i >> 8), cw + (int)(i & 255u), zn_s, en_s, best);
      }
    }
  }
}

// ---------------- z_q_st + loss + embed_sum + idx + counts (all f32) ----------------
// Round-6 lesson: atomic-free seg pipeline LOST 9us net vs this fused version.
__global__ __launch_bounds__(256, 1) void vq_scatter_v8(
    const float* __restrict__ z, const float* __restrict__ E,
    const unsigned long long* __restrict__ best, float* __restrict__ embsum,
    float* __restrict__ loss_sum, float* __restrict__ out_zq,
    float* __restrict__ out_idx, float* __restrict__ counts) {
  __shared__ float zt[256 * 33];     // staged z, overwritten in-place with z_q_st
  __shared__ int idx_s[32];
  __shared__ float wred[4];
  const int tid = threadIdx.x;
  const int tile = blockIdx.x;       // 0..1023
  const int b = tile >> 5;
  const int hw0 = (tile & 31) * 32;
  const float* zb = z + b * (D_ * HW_) + hw0;
  if (tid < 32) {
    int k = (int)(best[b * HW_ + hw0 + tid] & 1023ull);   // in-range by construction
    idx_s[tid] = k;
    out_idx[b * HW_ + hw0 + tid] = (float)k;
    atomicAdd(&counts[k], 1.0f);
  }
#pragma unroll
  for (int r = 0; r < 8; ++r) {
    int ii = r * 256 + tid;
    int d = ii >> 3, t4 = (ii & 7) * 4;
    float4 v = *(const float4*)(zb + d * HW_ + t4);
    float* p = zt + d * 33 + t4;
    p[0] = v.x; p[1] = v.y; p[2] = v.z; p[3] = v.w;
  }
  __syncthreads();

  const int w = tid >> 6, lane = tid & 63;
  float lsum = 0.f;
  for (int tt = 0; tt < 8; ++tt) {
    int t = w * 8 + tt;
    int k = idx_s[t];                      // wave-uniform
    const float* Er = E + k * D_;
    float* es = embsum + k * D_;
#pragma unroll
    for (int i = 0; i < 4; ++i) {
      int d = i * 64 + lane;
      float e = Er[d];
      float zv = zt[d * 33 + t];           // unique (t,d) owner -> safe in-place
      float df = __fsub_rn(zv, e);
      lsum += df * df;
      zt[d * 33 + t] = __fadd_rn(zv, __fsub_rn(e, zv));  // ref: z + (z_q - z)
      atomicAdd(es + d, zv);
    }
  }
#pragma unroll
  for (int o = 32; o > 0; o >>= 1) lsum += __shfl_down(lsum, o, 64);
  if (lane == 0) wred[w] = lsum;
  __syncthreads();
  if (tid == 0) atomicAdd(loss_sum, wred[0] + wred[1] + wred[2] + wred[3]);

  float* ob = out_zq + b * (D_ * HW_) + hw0;
#pragma unroll 4
  for (int r = 0; r < 32; ++r) {
    int d = r * 8 + (tid >> 5);
    int t = tid & 31;
    ob[d * HW_ + t] = zt[d * 33 + t];      // coalesced 128B-chunk f32 stores
  }
}

// ---------------- EMA cluster-size + n + loss finalize ----------------
__global__ void vq_newcs_v7(const float* __restrict__ cs_in, const float* __restrict__ counts,
                            float* __restrict__ newcs, float* __restrict__ nsum,
                            const float* __restrict__ loss_sum,
                            float* __restrict__ out_loss, float* __restrict__ out_ncs) {
  int k = blockIdx.x * 256 + threadIdx.x;
  float v = __fadd_rn(__fmul_rn(0.99f, cs_in[k]), __fmul_rn(0.01f, counts[k]));
  newcs[k] = v;
  out_ncs[k] = v;
  float s = v;
#pragma unroll
  for (int o = 32; o > 0; o >>= 1) s += __shfl_down(s, o, 64);
  __shared__ float w[4];
  if ((threadIdx.x & 63) == 0) w[threadIdx.x >> 6] = s;
  __syncthreads();
  if (threadIdx.x == 0) atomicAdd(nsum, w[0] + w[1] + w[2] + w[3]);
  if (k == 0) out_loss[0] = loss_sum[0] * (1.0f / 8388608.0f);
}

// ---------------- new_es + new_embedding ----------------
__global__ void vq_newemb_v7(const float* __restrict__ es_in, const float* __restrict__ embsum,
                             const float* __restrict__ newcs, const float* __restrict__ nsum,
                             float* __restrict__ out_emb, float* __restrict__ out_nes) {
  int k = blockIdx.x, d = threadIdx.x;
  float n = *nsum;
  float cs = (newcs[k] + 1e-5f) / (n + 1024.0f * 1e-5f) * n;   // ref formula order
  float es = __fadd_rn(__fmul_rn(0.99f, es_in[k * D_ + d]),
                       __fmul_rn(0.01f, embsum[k * D_ + d]));
  out_nes[k * D_ + d] = es;
  out_emb[k * D_ + d] = es / cs;
}

extern "C" void kernel_launch(void* const* d_in, const int* in_sizes, int n_in,
                              void* d_out, int out_size, void* d_ws, size_t ws_size,
                              hipStream_t stream) {
  (void)in_sizes; (void)n_in; (void)out_size; (void)ws_size;
  const float* z       = (const float*)d_in[0];
  const float* E       = (const float*)d_in[1];
  const float* ema_cs  = (const float*)d_in[2];
  const float* ema_es  = (const float*)d_in[3];
  float* out = (float*)d_out;
  char* ws = (char*)d_ws;
  unsigned long long* best = (unsigned long long*)(ws + WS_BEST);
  float* counts = (float*)(ws + WS_COUNTS);
  float* embsum = (float*)(ws + WS_EMBSUM);
  float* loss_s = (float*)(ws + WS_LOSS);
  float* nsum   = (float*)(ws + WS_NSUM);
  unsigned* enmax = (unsigned*)(ws + WS_ENMAX);
  float* newcs  = (float*)(ws + WS_NEWCS);
  float* enorm  = (float*)(ws + WS_ENORM);
  float* znorm  = (float*)(ws + WS_ZNORM);
  u16*   e16    = (u16*)(ws + WS_E16);
  float* zT     = out + O_ZQ;   // scratch: overwritten by vq_scatter at the end

  // 6 dispatches: norms+zt+best-init fused into vq_prep.
  hipMemsetAsync(ws + WS_ZERO0, 0, WS_ZEROLEN, stream);   // counts/embsum/loss/nsum/enmax
  vq_prep<<<dim3(1028), dim3(256), 0, stream>>>(z, E, znorm, enorm, e16, enmax,
                                                best, zT);
  vq_dist_mfma8<<<dim3(1024), dim3(256), 0, stream>>>(z, E, e16, zT, znorm, enorm,
                                                      enmax, best);
  vq_scatter_v8<<<dim3(1024), dim3(256), 0, stream>>>(z, E, best, embsum, loss_s,
                                                      out + O_ZQ, out + O_IDX, counts);
  vq_newcs_v7<<<dim3(4), dim3(256), 0, stream>>>(ema_cs, counts, newcs, nsum, loss_s,
                                                 out + O_LOSS, out + O_NCS);
  vq_newemb_v7<<<dim3(K_), dim3(256), 0, stream>>>(ema_es, embsum, newcs, nsum,
                                                   out + O_EMB, out + O_NES);
}

// Round 9
// 233.126 us; speedup vs baseline: 1.2265x; 1.2265x over previous
//
#include <hip/hip_runtime.h>

#define D_  256
#define K_  1024
#define HW_ 1024      // 32*32
#define N_  32768     // 32*HW_

// workspace layout (bytes)
#define WS_COUNTS  262144     // f32[1024]
#define WS_EMBSUM  266240     // f32[262144]
#define WS_LOSS    1314816    // f32
#define WS_NSUM    1314820    // f32
#define WS_ENMAX   1314824    // u32 (max ||e||^2 bits)
#define WS_ZERO0   262144     // zero range start
#define WS_ZEROLEN 1052684    // covers counts..enmax
#define WS_NEWCS   1314828    // f32[1024]
#define WS_ENORM   1318924    // f32[1024]
#define WS_E16     1454096    // fp16(512*E)[1024*256] = 512 KiB (16B aligned)
#define WS_TOTAL   1978384

// output offsets (f32 elements): (z_q_st, loss, indices, new_emb, new_cs, new_es)
#define O_ZQ   0
#define O_LOSS 8388608
#define O_IDX  8388609
#define O_EMB  8421377
#define O_NCS  8683521
#define O_NES  8684545

typedef unsigned short u16;
typedef _Float16 f16x8 __attribute__((ext_vector_type(8)));  // 8 f16 = 4 VGPRs
typedef float f32x4 __attribute__((ext_vector_type(4)));

// pack two f32 -> two f16 (HW v_cvt_f16_f32, rne)
__device__ __forceinline__ unsigned f16x2pack(float a, float b) {
  union { _Float16 h; unsigned short u; } ca, cb;
  ca.h = (_Float16)a; cb.h = (_Float16)b;
  return (unsigned)ca.u | ((unsigned)cb.u << 16);
}

// numpy pairwise_sum of 256 squares: two 128-halves, 8 accumulators,
// combine ((r0+r1)+(r2+r3))+((r4+r5)+(r6+r7)). __f*_rn blocks FMA contraction.
__device__ __forceinline__ float pw256_sq(const float* __restrict__ p, int stride) {
  float tot0 = 0.f, tot1 = 0.f;
#pragma unroll
  for (int h = 0; h < 2; ++h) {
    const float* q = p + h * 128 * stride;
    float r[8];
#pragma unroll
    for (int j = 0; j < 8; ++j) { float x = q[j * stride]; r[j] = __fmul_rn(x, x); }
    for (int i = 8; i < 128; i += 8)
#pragma unroll
      for (int j = 0; j < 8; ++j) {
        float x = q[(i + j) * stride];
        r[j] = __fadd_rn(r[j], __fmul_rn(x, x));
      }
    float s = __fadd_rn(__fadd_rn(__fadd_rn(r[0], r[1]), __fadd_rn(r[2], r[3])),
                        __fadd_rn(__fadd_rn(r[4], r[5]), __fadd_rn(r[6], r[7])));
    if (h == 0) tot0 = s; else tot1 = s;
  }
  return __fadd_rn(tot0, tot1);
}

// ---------------- E prep: ||e||^2 (np order), en_max, E->fp16*512 ----------------
__global__ void vq_eprep(const float* __restrict__ E, float* __restrict__ enorm,
                         u16* __restrict__ E16, unsigned* __restrict__ enmax) {
  int k = blockIdx.x * 256 + threadIdx.x;   // 4 blocks -> 0..1023
  float v = pw256_sq(E + k * D_, 1);
  enorm[k] = v;
  atomicMax(enmax, __float_as_uint(v));     // v > 0 -> bit-monotone
  unsigned* E16w = (unsigned*)E16;
  for (int wd = k; wd < (K_ * D_ / 2); wd += 1024) {
    float2 x = *(const float2*)(E + 2 * wd);
    E16w[wd] = f16x2pack(512.0f * x.x, 512.0f * x.y);
  }
}

// VALU-speed 16-lane min via DPP (quad_perm ^1, ^2, row_half_mirror, row_mirror)
template <int CTRL>
__device__ __forceinline__ float dppmin(float v) {
  int p = __builtin_amdgcn_update_dpp(0, __float_as_int(v), CTRL, 0xF, 0xF, true);
  return fminf(v, __int_as_float(p));
}

// Exact reference-numerics distance (np-order sequential fp32 FMA over d, then
// fl(fl(zn-2a)+en)); z row from LDS (contiguous f32), E row from global.
// Key=(score_bits<<32)|code -> LDS u64 atomicMin (block-final best; lowest
// code wins ties = np argmin). forceinline: only 2 call sites, both AFTER the
// MFMA loop (round-3 lesson: no calls with live acc/ef).
__device__ __forceinline__ void exact_update(
    const float* zrow, const float* __restrict__ E, int t, int c,
    const float* zn_s, const float* en_s, unsigned long long* best_s) {
  const float* ep = E + c * D_;
  float a = 0.f;
  for (int d0 = 0; d0 < 256; d0 += 8) {
    f32x4 z0 = *(const f32x4*)(zrow + d0);
    f32x4 z1 = *(const f32x4*)(zrow + d0 + 4);
    float4 e0 = *(const float4*)(ep + d0);
    float4 e1 = *(const float4*)(ep + d0 + 4);
    a = __fmaf_rn(z0[0], e0.x, a); a = __fmaf_rn(z0[1], e0.y, a);
    a = __fmaf_rn(z0[2], e0.z, a); a = __fmaf_rn(z0[3], e0.w, a);
    a = __fmaf_rn(z1[0], e1.x, a); a = __fmaf_rn(z1[1], e1.y, a);
    a = __fmaf_rn(z1[2], e1.z, a); a = __fmaf_rn(z1[3], e1.w, a);
  }
  float s = __fadd_rn(__fsub_rn(zn_s[t], __fmul_rn(2.0f, a)), en_s[c]);
  unsigned long long key = ((unsigned long long)__float_as_uint(s) << 32) | (unsigned)c;
  atomicMin(&best_s[t], key);
}

#define TCAP 96   // per-wave trigger list (expected ~24 used w/ fp16 margin)
#define ZP  260   // zs row pad: 260*4B = 1040 ≡ 0 mod 16 (b128-aligned rows);
                  // bank = (4t+d)%32 -> even 8-lanes-per-4-bank coverage on
                  // fragment reads (bandwidth-floor optimal), distinct on
                  // d-consecutive loops.

// ---------------- FUSED dist + scatter (one z read, zero zT, LDS best) ----------------
// 1024 blocks x 256 thr, ~39.6 KB LDS -> 4 blocks/CU. Block = 32 tokens x ALL
// 1024 codes => best is block-final (no cross-block merge) => scatter fuses in.
// Phase A: MFMA fp16 approx scores (z cvt'd f32->f16 on the fly from the LDS
// f32 tile), per-token running min, margin-gated trigger list, exact fp32
// re-verify into LDS best_s. Margin M = 2^-8*sqrt(zn*en_max)+5e-4 (2x the
// rigorous two-sided fp16 bound) -> reference argmin always triggers.
// Phase B: verbatim scatter body on the same LDS tile (loss, z_q_st in-place,
// embsum atomics, counts, idx). Phase-B memory ops of early blocks overlap
// phase-A latency stalls of co-resident blocks.
__global__ __launch_bounds__(256, 4) void vq_main(
    const float* __restrict__ z, const float* __restrict__ E,
    const u16* __restrict__ E16, const float* __restrict__ enorm,
    const unsigned* __restrict__ enmax,
    float* __restrict__ embsum, float* __restrict__ loss_sum,
    float* __restrict__ counts, float* __restrict__ out_zq,
    float* __restrict__ out_idx) {
  __shared__ __align__(16) float zs[32 * ZP];            // 33280 B, [tok][d]
  __shared__ float en_s[K_];                              // 4 KiB
  __shared__ float zn_s[32];
  __shared__ float mg_s[32];
  __shared__ unsigned rmin_s[32];                         // bits of (min ph)+4.0
  __shared__ unsigned long long best_s[32];
  __shared__ unsigned tcount[4];
  __shared__ unsigned tlist[4][TCAP];                     // 1.5 KiB
  __shared__ float wred[4];

  const int tid = threadIdx.x;
  const int tile = blockIdx.x;               // 0..1023
  const int bimg = tile >> 5;
  const int hw0 = (tile & 31) << 5;          // 32 tokens
  const float* zb = z + bimg * (D_ * HW_) + hw0;
  const int n0 = bimg * HW_ + hw0;

  // stage z f32 -> zs[t][d] (coalesced float4 global reads, scalar LDS writes)
#pragma unroll
  for (int r = 0; r < 8; ++r) {
    int ii = r * 256 + tid;
    int d = ii >> 3, t4 = (ii & 7) * 4;
    float4 v = *(const float4*)(zb + d * HW_ + t4);
    zs[(t4 + 0) * ZP + d] = v.x; zs[(t4 + 1) * ZP + d] = v.y;
    zs[(t4 + 2) * ZP + d] = v.z; zs[(t4 + 3) * ZP + d] = v.w;
  }
  for (int i = tid; i < K_; i += 256) en_s[i] = enorm[i];
  if (tid < 4) tcount[tid] = 0;
  __syncthreads();
  if (tid < 32) {
    float zn = pw256_sq(&zs[tid * ZP], 1);   // np order, bit-identical values
    zn_s[tid] = zn;
    float em = __uint_as_float(*enmax);
    mg_s[tid] = 0.00390625f * sqrtf(zn * em) + 5e-4f;  // fp16 margin (proven safe)
    rmin_s[tid] = 0xFFFFFFFFu;
    best_s[tid] = ~0ull;
  }
  __syncthreads();

  const int lane = tid & 63;
  const int w = tid >> 6;
  const int l15 = lane & 15, g = lane >> 4;
  const int cw = w * 256;                    // wave's code base
  const u16* Eb = E16 + (unsigned)(cw + l15) * D_ + g * 8;

  f16x8 efA[2], efB[2];
#pragma unroll
  for (int n = 0; n < 2; ++n)
    efA[n] = *(const f16x8*)(Eb + n * 16 * D_);          // prime: s=0 (ch0,kk0)

  f32x4 acc[2][2];

// one MFMA step: ef ping-pong (dist-1; best-measured), z fragment read as f32
// from zs + cvt to fp16 (same rne values as the old pre-converted tile).
// No branches, no calls in the loop.
#define MSTEP(S, EFU, EFF, SN)                                                   \
  {                                                                              \
    const int kk_ = (S) & 7;                                                     \
    {                                                                            \
      const int cn_ = (SN) >> 3, kn_ = (SN) & 7;                                 \
      _Pragma("unroll")                                                          \
      for (int n = 0; n < 2; ++n)                                                \
        EFF[n] = *(const f16x8*)(Eb + (cn_ * 32 + n * 16) * D_ + kn_ * 32);      \
    }                                                                            \
    f16x8 zf_[2];                                                                \
    _Pragma("unroll")                                                            \
    for (int m = 0; m < 2; ++m) {                                                \
      const float* zr = zs + (m * 16 + l15) * ZP + kk_ * 32 + g * 8;             \
      f32x4 lo = *(const f32x4*)zr;                                              \
      f32x4 hi = *(const f32x4*)(zr + 4);                                        \
      f16x8 zc;                                                                  \
      _Pragma("unroll")                                                          \
      for (int j = 0; j < 4; ++j) {                                              \
        zc[j] = (_Float16)lo[j]; zc[4 + j] = (_Float16)hi[j];                    \
      }                                                                          \
      zf_[m] = zc;                                                               \
    }                                                                            \
    _Pragma("unroll")                                                            \
    for (int m = 0; m < 2; ++m)                                                  \
      _Pragma("unroll")                                                          \
      for (int n = 0; n < 2; ++n)                                                \
        acc[m][n] = __builtin_amdgcn_mfma_f32_16x16x32_f16(zf_[m], EFU[n],       \
                                                           acc[m][n], 0, 0, 0);  \
  }

  for (int s2 = 0; s2 < 64; s2 += 2) {      // 8 chunks x 8 kk
    if ((s2 & 7) == 0) {
      f32x4 z4 = {0.f, 0.f, 0.f, 0.f};
#pragma unroll
      for (int m = 0; m < 2; ++m)
#pragma unroll
        for (int n = 0; n < 2; ++n) acc[m][n] = z4;
    }
    MSTEP(s2, efA, efB, s2 + 1)
    MSTEP(s2 + 1, efB, efA, (s2 + 2) & 63)   // tail wrap value never consumed
    if ((s2 & 7) == 6) {                     // chunk end
      const int cb = cw + (s2 >> 3) * 32;
      // ph = en - 2*(A/512) = fma(-1/256, A, en); D: col=l15(code), row=g*4+r(tok)
      float enc[2];
#pragma unroll
      for (int n = 0; n < 2; ++n) enc[n] = en_s[cb + n * 16 + l15];
#pragma unroll
      for (int m = 0; m < 2; ++m)
#pragma unroll
        for (int n = 0; n < 2; ++n)
#pragma unroll
          for (int r = 0; r < 4; ++r)
            acc[m][n][r] = __builtin_fmaf(-0.00390625f, acc[m][n][r], enc[n]);
#pragma unroll
      for (int m = 0; m < 2; ++m)
#pragma unroll
        for (int r = 0; r < 4; ++r) {
          float v = fminf(acc[m][0][r], acc[m][1][r]);
          v = dppmin<0xB1>(v);     // ^1
          v = dppmin<0x4E>(v);     // ^2
          v = dppmin<0x141>(v);    // row_half_mirror
          v = dppmin<0x140>(v);    // row_mirror
          if (l15 == 0) atomicMin(&rmin_s[m * 16 + g * 4 + r], __float_as_uint(v + 4.0f));
        }
#pragma unroll
      for (int m = 0; m < 2; ++m)
#pragma unroll
        for (int r = 0; r < 4; ++r) {
          int t = m * 16 + g * 4 + r;
          float thr = (__uint_as_float(rmin_s[t]) - 4.0f) + mg_s[t];
#pragma unroll
          for (int n = 0; n < 2; ++n) {
            if (acc[m][n][r] <= thr) {
              unsigned pos = atomicAdd(&tcount[w], 1u);
              if (pos < TCAP)
                tlist[w][pos] = ((unsigned)t << 16) | (unsigned)(cb + n * 16 + l15);
            }
          }
        }
    }
  }
#undef MSTEP

  // drain own wave's triggers: exact recompute (LDS z row + global E) -> best_s
  {
    unsigned cnt = tcount[w];
    if (cnt <= TCAP) {
      for (unsigned basei = 0; basei < cnt; basei += 64) {
        unsigned i = basei + (unsigned)lane;
        if (i < cnt) {
          unsigned e = tlist[w][i];
          int t = (int)(e >> 16), c = (int)(e & 1023u);
          exact_update(&zs[t * ZP], E, t, c, zn_s, en_s, best_s);
        }
      }
    } else {
      // overflow (astronomically rare): exact-verify wave's whole 32x256 tile
      for (unsigned i = (unsigned)lane; i < 32u * 256u; i += 64) {
        int t = (int)(i >> 8), c = cw + (int)(i & 255u);
        exact_update(&zs[t * ZP], E, t, c, zn_s, en_s, best_s);
      }
    }
  }
  __syncthreads();   // best_s final; zs reads done -> phase B may overwrite

  // ---------------- phase B: scatter body on the same LDS tile ----------------
  if (tid < 32) {
    int k = (int)(best_s[tid] & 1023ull);
    out_idx[n0 + tid] = (float)k;
    atomicAdd(&counts[k], 1.0f);
  }
  float lsum = 0.f;
  for (int tt = 0; tt < 8; ++tt) {
    int t = w * 8 + tt;
    int k = (int)(best_s[t] & 1023ull);    // wave-uniform
    const float* Er = E + k * D_;
    float* es = embsum + k * D_;
#pragma unroll
    for (int i = 0; i < 4; ++i) {
      int d = i * 64 + lane;
      float e = Er[d];
      float zv = zs[t * ZP + d];           // unique (t,d) owner -> safe in-place
      float df = __fsub_rn(zv, e);
      lsum += df * df;
      zs[t * ZP + d] = __fadd_rn(zv, __fsub_rn(e, zv));  // ref: z + (z_q - z)
      atomicAdd(es + d, zv);
    }
  }
#pragma unroll
  for (int o = 32; o > 0; o >>= 1) lsum += __shfl_down(lsum, o, 64);
  if (lane == 0) wred[w] = lsum;
  __syncthreads();
  if (tid == 0) atomicAdd(loss_sum, wred[0] + wred[1] + wred[2] + wred[3]);

  float* ob = out_zq + bimg * (D_ * HW_) + hw0;
#pragma unroll 4
  for (int r = 0; r < 32; ++r) {
    int d = r * 8 + (tid >> 5);
    int t = tid & 31;
    ob[d * HW_ + t] = zs[t * ZP + d];      // coalesced 128B-chunk f32 stores
  }
}

// ---------------- EMA cluster-size + n + loss finalize ----------------
__global__ void vq_newcs_v7(const float* __restrict__ cs_in, const float* __restrict__ counts,
                            float* __restrict__ newcs, float* __restrict__ nsum,
                            const float* __restrict__ loss_sum,
                            float* __restrict__ out_loss, float* __restrict__ out_ncs) {
  int k = blockIdx.x * 256 + threadIdx.x;
  float v = __fadd_rn(__fmul_rn(0.99f, cs_in[k]), __fmul_rn(0.01f, counts[k]));
  newcs[k] = v;
  out_ncs[k] = v;
  float s = v;
#pragma unroll
  for (int o = 32; o > 0; o >>= 1) s += __shfl_down(s, o, 64);
  __shared__ float w[4];
  if ((threadIdx.x & 63) == 0) w[threadIdx.x >> 6] = s;
  __syncthreads();
  if (threadIdx.x == 0) atomicAdd(nsum, w[0] + w[1] + w[2] + w[3]);
  if (k == 0) out_loss[0] = loss_sum[0] * (1.0f / 8388608.0f);
}

// ---------------- new_es + new_embedding ----------------
__global__ void vq_newemb_v7(const float* __restrict__ es_in, const float* __restrict__ embsum,
                             const float* __restrict__ newcs, const float* __restrict__ nsum,
                             float* __restrict__ out_emb, float* __restrict__ out_nes) {
  int k = blockIdx.x, d = threadIdx.x;
  float n = *nsum;
  float cs = (newcs[k] + 1e-5f) / (n + 1024.0f * 1e-5f) * n;   // ref formula order
  float es = __fadd_rn(__fmul_rn(0.99f, es_in[k * D_ + d]),
                       __fmul_rn(0.01f, embsum[k * D_ + d]));
  out_nes[k * D_ + d] = es;
  out_emb[k * D_ + d] = es / cs;
}

extern "C" void kernel_launch(void* const* d_in, const int* in_sizes, int n_in,
                              void* d_out, int out_size, void* d_ws, size_t ws_size,
                              hipStream_t stream) {
  (void)in_sizes; (void)n_in; (void)out_size; (void)ws_size;
  const float* z       = (const float*)d_in[0];
  const float* E       = (const float*)d_in[1];
  const float* ema_cs  = (const float*)d_in[2];
  const float* ema_es  = (const float*)d_in[3];
  float* out = (float*)d_out;
  char* ws = (char*)d_ws;
  float* counts = (float*)(ws + WS_COUNTS);
  float* embsum = (float*)(ws + WS_EMBSUM);
  float* loss_s = (float*)(ws + WS_LOSS);
  float* nsum   = (float*)(ws + WS_NSUM);
  unsigned* enmax = (unsigned*)(ws + WS_ENMAX);
  float* newcs  = (float*)(ws + WS_NEWCS);
  float* enorm  = (float*)(ws + WS_ENORM);
  u16*   e16    = (u16*)(ws + WS_E16);

  // 5 dispatches: dist+scatter fused; zT/prep-z/best-memset eliminated.
  hipMemsetAsync(ws + WS_ZERO0, 0, WS_ZEROLEN, stream);   // counts/embsum/loss/nsum/enmax
  vq_eprep<<<dim3(4), dim3(256), 0, stream>>>(E, enorm, e16, enmax);
  vq_main<<<dim3(1024), dim3(256), 0, stream>>>(z, E, e16, enorm, enmax,
                                                embsum, loss_s, counts,
                                                out + O_ZQ, out + O_IDX);
  vq_newcs_v7<<<dim3(4), dim3(256), 0, stream>>>(ema_cs, counts, newcs, nsum, loss_s,
                                                 out + O_LOSS, out + O_NCS);
  vq_newemb_v7<<<dim3(K_), dim3(256), 0, stream>>>(ema_es, embsum, newcs, nsum,
                                                   out + O_EMB, out + O_NES);
}